// Round 5
// baseline (2228.317 us; speedup 1.0000x reference)
//
#include <hip/hip_runtime.h>
#include <hip/hip_bf16.h>
#include <cstdint>
#include <cstddef>

typedef unsigned short u16;
typedef __attribute__((ext_vector_type(4))) float f32x4;
typedef __attribute__((ext_vector_type(8))) short short8;

#define B_SZ 256
#define T_SZ 256
#define IN_SZ 64
#define H_SZ 512
#define G3 1536
#define BH (256 * 512)   // elements per h ring slot

__device__ __forceinline__ u16 f2bf(float f) {
  union { float f; unsigned int i; } v; v.f = f;
  unsigned int x = v.i;
  unsigned int r = (x + 0x7fffu + ((x >> 16) & 1u)) >> 16;  // RNE
  return (u16)r;
}
__device__ __forceinline__ float sigmoidf_(float x) { return 1.0f / (1.0f + __expf(-x)); }
__device__ __forceinline__ float tanhf_(float x) {
  float e = __expf(-2.0f * x); return (1.0f - e) / (1.0f + e);
}
// wave-wide spin: lane i polls flag i (64 flags). Relaxed (same-XCD L2).
__device__ __forceinline__ void wave_spin(int* f, int v) {
  int* p = f + (threadIdx.x & 63);
  int cap = 0;
  while (__hip_atomic_load(p, __ATOMIC_RELAXED, __HIP_MEMORY_SCOPE_AGENT) < v) {
    __builtin_amdgcn_s_sleep(1);
    if (++cap > 300000) break;  // hang breaker; never hit in normal runs
  }
  asm volatile("" ::: "memory");  // no load may hoist above the flag check
}

// ---------------- weight-norm + bf16 cast: one wave per row ----------------
__global__ __launch_bounds__(256)
void norm_cast_kernel(const float* __restrict__ v, const float* __restrict__ g,
                      u16* __restrict__ out, int cols) {
  int row = blockIdx.x * 4 + (threadIdx.x >> 6);
  int lane = threadIdx.x & 63;
  const float* vr = v + (size_t)row * cols;
  float s = 0.f;
  for (int c = lane; c < cols; c += 64) { float t = vr[c]; s += t * t; }
  for (int o = 32; o; o >>= 1) s += __shfl_xor(s, o);
  float scale = g[row] / sqrtf(s);
  for (int c = lane; c < cols; c += 64) out[(size_t)row * cols + c] = f2bf(vr[c] * scale);
}

__global__ __launch_bounds__(256)
void castx_kernel(const float* __restrict__ x, u16* __restrict__ xb) {
  int i = blockIdx.x * 256 + threadIdx.x;
  float4 v = ((const float4*)x)[i];
  ushort4 o;
  o.x = f2bf(v.x); o.y = f2bf(v.y); o.z = f2bf(v.z); o.w = f2bf(v.w);
  ((ushort4*)xb)[i] = o;
}

// ---------------- fused 2-layer persistent GRU, per-wave agents -------------
// 256 blocks x 256 thr, 1 blk/CU (LDS 96KB). Block claims role on ITS XCD:
// group g = xcd (32 batch rows), r<16 -> L0 slice r, r>=16 -> L1 slice r-16.
// Each WAVE is an independent agent (16 rows x 16 units): no __syncthreads in
// the loop; per-wave flags (64/group/layer). Whh fragments live in REGISTERS
// (48 x short8 = 192 VGPR); L0 also keeps Wih0 in regs; L1 keeps the full
// Wih1 slice in LDS (96KB, XOR-swizzled). XCD-local relaxed flags + L1-only
// buffer_inv; no agent fences anywhere in the loop.
__global__ __launch_bounds__(256, 1)
void fused_rnn_kernel(const u16* __restrict__ whh0, const u16* __restrict__ wih0,
                      const float* __restrict__ bih0p, const float* __restrict__ bhh0p,
                      const u16* __restrict__ whh1, const u16* __restrict__ wih1,
                      const float* __restrict__ bih1p, const float* __restrict__ bhh1p,
                      const u16* __restrict__ xb, u16* __restrict__ h0ring,
                      u16* __restrict__ h1ring, float* __restrict__ h1fin,
                      int* __restrict__ flags, int* __restrict__ claim) {
  __shared__ u16 Wx1[96 * 512];   // L1: full Wih1 slice, swizzled, 96KB
  __shared__ int role_sh;

  const int tid = threadIdx.x;
  if (tid == 0) {
    int xcd;
    asm volatile("s_getreg_b32 %0, hwreg(HW_REG_XCC_ID)" : "=s"(xcd));
    xcd &= 7;
    int r = atomicAdd(&claim[xcd], 1);          // device-scope, coherent
    role_sh = xcd * 64 + r;
  }
  __syncthreads();
  const int g = role_sh >> 6;        // batch group == XCD
  const int r = role_sh & 63;
  if (r >= 32) return;               // can't happen (pigeonhole 32/XCD)
  const int L = r >> 4;
  const int s = r & 15;              // hidden slice (32 units)

  const int lane = tid & 63;
  const int wv = tid >> 6;           // wave id 0..3
  const int wm = wv >> 1;            // 16-row tile
  const int wk = wv & 1;             // 16-unit half
  const int q = lane >> 4;
  const int ul = wk * 16 + (lane & 15);   // local unit 0..31
  const int gu = s * 32 + ul;
  const int arow = g * 32 + wm * 16 + (lane & 15);
  const int swz = (ul & 7) << 4;
  const int wid = s * 4 + wv;        // wave-flag index within group/layer

  // L1: stage full Wih1 slice (96 rows x 1024B) swizzled into LDS
  if (L == 1) {
    for (int idx = tid; idx < 6144; idx += 256) {
      int rr = idx >> 6, c16 = idx & 63;
      int grow = (rr >> 5) * 512 + s * 32 + (rr & 31);
      int sb = (c16 << 4) ^ ((rr & 7) << 4);
      uint4 vv = *(const uint4*)((const char*)wih1 + (size_t)grow * 1024 + sb);
      *(uint4*)((char*)Wx1 + rr * 1024 + (c16 << 4)) = vv;
    }
  }

  // Whh fragments -> registers (48 x short8 = 192 VGPR per lane)
  const u16* whhp = L ? whh1 : whh0;
  short8 whf[3][16];
  #pragma unroll
  for (int g3 = 0; g3 < 3; ++g3)
    #pragma unroll
    for (int kk = 0; kk < 16; ++kk)
      whf[g3][kk] = *(const short8*)(whhp + (size_t)(g3 * 512 + s * 32 + ul) * 512
                                     + kk * 32 + q * 8);
  // L0: Wih0 fragments -> registers (6 x short8)
  short8 wxf[3][2];
  if (L == 0) {
    #pragma unroll
    for (int g3 = 0; g3 < 3; ++g3)
      #pragma unroll
      for (int k2 = 0; k2 < 2; ++k2)
        wxf[g3][k2] = *(const short8*)(wih0 + (size_t)(g3 * 512 + s * 32 + ul) * 64
                                       + k2 * 32 + q * 8);
  }
  const float* bip = L ? bih1p : bih0p;
  const float* bhp = L ? bhh1p : bhh0p;
  const float bi_r = bip[s * 32 + ul], bi_z = bip[512 + s * 32 + ul], bi_n = bip[1024 + s * 32 + ul];
  const float bh_r = bhp[s * 32 + ul], bh_z = bhp[512 + s * 32 + ul], bh_n = bhp[1024 + s * 32 + ul];

  __syncthreads();   // LDS staging visible; last barrier before the loop

  int* h0f = flags + g * 64;         // 64 L0 wave-flags of this group
  int* h1f = flags + 512 + g * 64;   // 64 L1 wave-flags of this group
  float h_reg[4] = {0.f, 0.f, 0.f, 0.f};

  if (L == 0) {
    for (int t = 0; t < T_SZ; ++t) {
      f32x4 accr = {0.f,0.f,0.f,0.f}, accz = {0.f,0.f,0.f,0.f};
      f32x4 axn  = {0.f,0.f,0.f,0.f}, ahn  = {0.f,0.f,0.f,0.f};
      // gx0: independent of peers -> before spins
      const u16* xp = xb + ((size_t)arow * T_SZ + t) * 64;
      short8 ax0 = *(const short8*)(xp + q * 8);
      short8 ax1 = *(const short8*)(xp + 32 + q * 8);
      accr = __builtin_amdgcn_mfma_f32_16x16x32_bf16(ax0, wxf[0][0], accr, 0, 0, 0);
      accz = __builtin_amdgcn_mfma_f32_16x16x32_bf16(ax0, wxf[1][0], accz, 0, 0, 0);
      axn  = __builtin_amdgcn_mfma_f32_16x16x32_bf16(ax0, wxf[2][0], axn, 0, 0, 0);
      accr = __builtin_amdgcn_mfma_f32_16x16x32_bf16(ax1, wxf[0][1], accr, 0, 0, 0);
      accz = __builtin_amdgcn_mfma_f32_16x16x32_bf16(ax1, wxf[1][1], accz, 0, 0, 0);
      axn  = __builtin_amdgcn_mfma_f32_16x16x32_bf16(ax1, wxf[2][1], axn, 0, 0, 0);
      if (t > 0) wave_spin(h0f, t);            // peers' h0(t-1)
      if (t >= 8) wave_spin(h1f, t - 7);       // WAR guard on ring slot t&7
      asm volatile("buffer_inv sc0" ::: "memory");   // L1-only invalidate
      if (t > 0) {
        const u16* hp = h0ring + (size_t)((t - 1) & 7) * BH + (size_t)arow * 512;
        #pragma unroll
        for (int kk = 0; kk < 16; ++kk) {
          short8 a = *(const short8*)(hp + kk * 32 + q * 8);
          accr = __builtin_amdgcn_mfma_f32_16x16x32_bf16(a, whf[0][kk], accr, 0, 0, 0);
          accz = __builtin_amdgcn_mfma_f32_16x16x32_bf16(a, whf[1][kk], accz, 0, 0, 0);
          ahn  = __builtin_amdgcn_mfma_f32_16x16x32_bf16(a, whf[2][kk], ahn, 0, 0, 0);
        }
      }
      u16* dst = h0ring + (size_t)(t & 7) * BH + (size_t)(g * 32 + wm * 16) * 512 + gu;
      #pragma unroll
      for (int r2 = 0; r2 < 4; ++r2) {
        float rr = sigmoidf_(accr[r2] + bi_r + bh_r);
        float zz = sigmoidf_(accz[r2] + bi_z + bh_z);
        float nn = tanhf_(axn[r2] + bi_n + rr * (ahn[r2] + bh_n));
        float hv = (1.0f - zz) * nn + zz * h_reg[r2];
        h_reg[r2] = hv;
        dst[(size_t)(q * 4 + r2) * 512] = f2bf(hv);
      }
      asm volatile("s_waitcnt vmcnt(0)" ::: "memory");  // publish drained to L2
      if (lane == 0)
        __hip_atomic_store(&h0f[wid], t + 1, __ATOMIC_RELAXED, __HIP_MEMORY_SCOPE_AGENT);
    }
  } else {
    for (int t = 0; t < T_SZ; ++t) {
      f32x4 accr = {0.f,0.f,0.f,0.f}, accz = {0.f,0.f,0.f,0.f};
      f32x4 axn  = {0.f,0.f,0.f,0.f}, ahn  = {0.f,0.f,0.f,0.f};
      wave_spin(h0f, t + 1);                   // h0(t) ready
      asm volatile("buffer_inv sc0" ::: "memory");
      {  // gx1 = Wih1 . h0(t)  (LDS B-operands) — hides the h1-peer wait
        const u16* hp0 = h0ring + (size_t)(t & 7) * BH + (size_t)arow * 512;
        #pragma unroll
        for (int kk = 0; kk < 16; ++kk) {
          short8 a0 = *(const short8*)(hp0 + kk * 32 + q * 8);
          int bofs = (kk * 64 + q * 16) ^ swz;
          short8 br = *(const short8*)((const char*)Wx1 + (size_t)ul * 1024 + bofs);
          short8 bz = *(const short8*)((const char*)Wx1 + (size_t)(32 + ul) * 1024 + bofs);
          short8 bn = *(const short8*)((const char*)Wx1 + (size_t)(64 + ul) * 1024 + bofs);
          accr = __builtin_amdgcn_mfma_f32_16x16x32_bf16(a0, br, accr, 0, 0, 0);
          accz = __builtin_amdgcn_mfma_f32_16x16x32_bf16(a0, bz, accz, 0, 0, 0);
          axn  = __builtin_amdgcn_mfma_f32_16x16x32_bf16(a0, bn, axn, 0, 0, 0);
        }
      }
      if (t > 0) {
        wave_spin(h1f, t);                     // peers' h1(t-1)
        const u16* hp1 = h1ring + (size_t)((t - 1) & 3) * BH + (size_t)arow * 512;
        #pragma unroll
        for (int kk = 0; kk < 16; ++kk) {
          short8 a1 = *(const short8*)(hp1 + kk * 32 + q * 8);
          accr = __builtin_amdgcn_mfma_f32_16x16x32_bf16(a1, whf[0][kk], accr, 0, 0, 0);
          accz = __builtin_amdgcn_mfma_f32_16x16x32_bf16(a1, whf[1][kk], accz, 0, 0, 0);
          ahn  = __builtin_amdgcn_mfma_f32_16x16x32_bf16(a1, whf[2][kk], ahn, 0, 0, 0);
        }
      }
      u16* dst = h1ring + (size_t)(t & 3) * BH + (size_t)(g * 32 + wm * 16) * 512 + gu;
      #pragma unroll
      for (int r2 = 0; r2 < 4; ++r2) {
        float rr = sigmoidf_(accr[r2] + bi_r + bh_r);
        float zz = sigmoidf_(accz[r2] + bi_z + bh_z);
        float nn = tanhf_(axn[r2] + bi_n + rr * (ahn[r2] + bh_n));
        float hv = (1.0f - zz) * nn + zz * h_reg[r2];
        h_reg[r2] = hv;
        dst[(size_t)(q * 4 + r2) * 512] = f2bf(hv);
        if (t == T_SZ - 1)
          h1fin[(size_t)(g * 32 + wm * 16 + q * 4 + r2) * 512 + gu] = hv;
      }
      asm volatile("s_waitcnt vmcnt(0)" ::: "memory");
      if (lane == 0)
        __hip_atomic_store(&h1f[wid], t + 1, __ATOMIC_RELAXED, __HIP_MEMORY_SCOPE_AGENT);
    }
  }
}

// ---------------- final FC: out[b] = h1[b,:] . w_fc + b_fc ------------------
__global__ __launch_bounds__(256)
void fc_kernel(const float* __restrict__ h, const float* __restrict__ w,
               const float* __restrict__ bfc, float* __restrict__ out) {
  int b = blockIdx.x; int tid = threadIdx.x;
  float s = h[(size_t)b * 512 + tid] * w[tid] + h[(size_t)b * 512 + tid + 256] * w[tid + 256];
  for (int o = 32; o; o >>= 1) s += __shfl_xor(s, o);
  __shared__ float ws4[4];
  if ((tid & 63) == 0) ws4[tid >> 6] = s;
  __syncthreads();
  if (tid == 0) out[b] = ws4[0] + ws4[1] + ws4[2] + ws4[3] + bfc[0];
}

extern "C" void kernel_launch(void* const* d_in, const int* in_sizes, int n_in,
                              void* d_out, int out_size, void* d_ws, size_t ws_size,
                              hipStream_t stream) {
  const float* x     = (const float*)d_in[0];
  const float* v_ih0 = (const float*)d_in[1];
  const float* g_ih0 = (const float*)d_in[2];
  const float* b_ih0 = (const float*)d_in[3];
  const float* v_hh0 = (const float*)d_in[4];
  const float* g_hh0 = (const float*)d_in[5];
  const float* b_hh0 = (const float*)d_in[6];
  const float* v_ih1 = (const float*)d_in[7];
  const float* g_ih1 = (const float*)d_in[8];
  const float* b_ih1 = (const float*)d_in[9];
  const float* v_hh1 = (const float*)d_in[10];
  const float* g_hh1 = (const float*)d_in[11];
  const float* b_hh1 = (const float*)d_in[12];
  const float* w_fc  = (const float*)d_in[13];
  const float* b_fc  = (const float*)d_in[14];
  float* out = (float*)d_out;

  char* w = (char*)d_ws;
  size_t off = 0;
  auto alloc = [&](size_t bytes) -> char* {
    char* p = w + off; off += (bytes + 255) & ~(size_t)255; return p;
  };
  int*   flags  = (int*)alloc(4096 + 256);   // [2][8][64] wave-flags, then claim[8]
  int*   claim  = flags + 1024;
  float* h1fin  = (float*)alloc((size_t)256 * 512 * 4);
  u16*   h0ring = (u16*)alloc((size_t)8 * BH * 2);
  u16*   h1ring = (u16*)alloc((size_t)4 * BH * 2);
  u16*   xb     = (u16*)alloc((size_t)B_SZ * T_SZ * IN_SZ * 2);
  u16*   wih0   = (u16*)alloc((size_t)G3 * IN_SZ * 2);
  u16*   whh0   = (u16*)alloc((size_t)G3 * H_SZ * 2);
  u16*   wih1   = (u16*)alloc((size_t)G3 * H_SZ * 2);
  u16*   whh1   = (u16*)alloc((size_t)G3 * H_SZ * 2);
  if (off > ws_size) return;  // ~18MB; evidenced ws is far larger

  hipMemsetAsync(flags, 0, 4096 + 256, stream);
  norm_cast_kernel<<<384, 256, 0, stream>>>(v_ih0, g_ih0, wih0, IN_SZ);
  norm_cast_kernel<<<384, 256, 0, stream>>>(v_hh0, g_hh0, whh0, H_SZ);
  norm_cast_kernel<<<384, 256, 0, stream>>>(v_ih1, g_ih1, wih1, H_SZ);
  norm_cast_kernel<<<384, 256, 0, stream>>>(v_hh1, g_hh1, whh1, H_SZ);
  castx_kernel<<<4096, 256, 0, stream>>>(x, xb);

  fused_rnn_kernel<<<256, 256, 0, stream>>>(whh0, wih0, b_ih0, b_hh0,
                                            whh1, wih1, b_ih1, b_hh1,
                                            xb, h0ring, h1ring, h1fin,
                                            flags, claim);
  fc_kernel<<<256, 256, 0, stream>>>(h1fin, w_fc, b_fc, out);
}